// Round 8
// baseline (13893.927 us; speedup 1.0000x reference)
//
#include <hip/hip_runtime.h>

#define BB 256
#define TT 256
#define II 256
#define HH 1024
#define LL 128
#define K1 1280   // HH + II
#define GN 3072   // 3*HH
#define BBHH (BB * HH)

#define RP 49     // red row stride (floats)
#define GP 17     // gxn row stride
#define PP 20     // pred row stride

typedef short s8v    __attribute__((ext_vector_type(8)));
typedef float f32x4  __attribute__((ext_vector_type(4)));
typedef float f4v    __attribute__((ext_vector_type(4)));
typedef unsigned long long u64;

__device__ __forceinline__ unsigned short f2bf(float f) {
    unsigned u = __float_as_uint(f);
    u += 0x7fffu + ((u >> 16) & 1u);
    return (unsigned short)(u >> 16);
}
__device__ __forceinline__ float bf2f(unsigned short h) {
    return __uint_as_float(((unsigned)h) << 16);
}
__device__ __forceinline__ float sigm(float x) { return 1.0f / (1.0f + __expf(-x)); }

__device__ __forceinline__ s8v cvt8(const float* __restrict__ p) {
    const f4v lo = *(const f4v*)p;
    const f4v hi = *(const f4v*)(p + 4);
    s8v r;
    r[0] = (short)f2bf(lo[0]); r[1] = (short)f2bf(lo[1]);
    r[2] = (short)f2bf(lo[2]); r[3] = (short)f2bf(lo[3]);
    r[4] = (short)f2bf(hi[0]); r[5] = (short)f2bf(hi[1]);
    r[6] = (short)f2bf(hi[2]); r[7] = (short)f2bf(hi[3]);
    return r;
}

__device__ __forceinline__ s8v hload16a(const unsigned short* p) {
    union { u64 q[2]; s8v v; } u;
    u.q[0] = __hip_atomic_load((const u64*)p, __ATOMIC_RELAXED, __HIP_MEMORY_SCOPE_AGENT);
    u.q[1] = __hip_atomic_load((const u64*)p + 1, __ATOMIC_RELAXED, __HIP_MEMORY_SCOPE_AGENT);
    return u.v;
}
template<int FRESH> __device__ __forceinline__ s8v ld16h(const unsigned short* p) {
    if constexpr (FRESH) return *(const s8v*)p;
    else return hload16a(p);
}
template<int FRESH> __device__ __forceinline__ u64 ld8h(const unsigned short* p) {
    if constexpr (FRESH) return *(const u64*)p;
    else return __hip_atomic_load((const u64*)p, __ATOMIC_RELAXED, __HIP_MEMORY_SCOPE_AGENT);
}
__device__ __forceinline__ void st8h(unsigned short* p, u64 v) {
    __hip_atomic_store((u64*)p, v, __ATOMIC_RELAXED, __HIP_MEMORY_SCOPE_AGENT);
}

__device__ __forceinline__ void poll_pair(const unsigned* p, unsigned t) {
    if (t == 0) return;
    int guard = 0;
    for (;;) {
        u64 v = __hip_atomic_load((const u64*)p, __ATOMIC_RELAXED, __HIP_MEMORY_SCOPE_AGENT);
        if ((unsigned)v >= t && (unsigned)(v >> 32) >= t) return;
        __builtin_amdgcn_s_sleep(1);
        if (++guard > (1 << 17)) return;
    }
}
__device__ __forceinline__ void poll_range16(const unsigned* p0, int lr, unsigned t) {
    if (t == 0) return;
    int guard = 0;
    for (;;) {
        unsigned v = __hip_atomic_load(p0 + lr, __ATOMIC_RELAXED, __HIP_MEMORY_SCOPE_AGENT);
        if (__ballot(v >= t) == ~0ull) break;
        __builtin_amdgcn_s_sleep(1);
        if (++guard > (1 << 17)) break;
    }
    asm volatile("" ::: "memory");
}
__device__ __forceinline__ void poll_range64(const unsigned* p0, int lane, unsigned t) {
    if (t == 0) return;
    int guard = 0;
    for (;;) {
        unsigned v = __hip_atomic_load(p0 + lane, __ATOMIC_RELAXED, __HIP_MEMORY_SCOPE_AGENT);
        if (__ballot(v >= t) == ~0ull) break;
        __builtin_amdgcn_s_sleep(1);
        if (++guard > (1 << 17)) break;
    }
    asm volatile("" ::: "memory");
}

// ---- prep kernels (unchanged, proven) ----
__global__ void k_prep_w(const float* __restrict__ Whh, const float* __restrict__ Wih,
                         unsigned short* __restrict__ Wperm) {
    int o = blockIdx.x;
    int ntt = o / 48, q = o - ntt * 48;
    int gate = q >> 4, j = ntt * 16 + (q & 15);
    int src = gate * HH + j;
    const float* sh = Whh + (size_t)src * HH;
    const float* si = Wih + (size_t)src * II;
    unsigned short* dst = Wperm + (size_t)o * K1;
    for (int k = threadIdx.x; k < K1; k += 256)
        dst[k] = f2bf(k < HH ? sh[k] : si[k - HH]);
}

__global__ void k_prep_misc(const float* __restrict__ bih, const float* __restrict__ bhh,
                            const float* __restrict__ Wout,
                            float* __restrict__ bihp, float* __restrict__ bhhp,
                            unsigned short* __restrict__ Woutb) {
    int idx = blockIdx.x * 256 + threadIdx.x;
    if (idx < GN) {
        int ntt = idx / 48, q = idx - ntt * 48;
        int gate = q >> 4, j = ntt * 16 + (q & 15);
        int src = gate * HH + j;
        bihp[idx] = bih[src];
        bhhp[idx] = bhh[src];
    }
    for (size_t i = (size_t)blockIdx.x * 256 + threadIdx.x; i < (size_t)II * HH;
         i += (size_t)gridDim.x * 256)
        Woutb[i] = f2bf(Wout[i]);
}

__global__ void k_h0(const float* __restrict__ z, const float* __restrict__ Wz,
                     const float* __restrict__ bz, unsigned short* __restrict__ hbuf) {
    int b = blockIdx.x;
    int j0 = threadIdx.x * 4;
    const f4v* zr = (const f4v*)(z + (size_t)b * LL);
    u64 packed = 0;
#pragma unroll
    for (int jj = 0; jj < 4; ++jj) {
        int j = j0 + jj;
        const f4v* wr = (const f4v*)(Wz + (size_t)j * LL);
        float s = bz[j];
#pragma unroll
        for (int i = 0; i < LL / 4; ++i) {
            f4v a = zr[i], w = wr[i];
            s += a[0] * w[0] + a[1] * w[1] + a[2] * w[2] + a[3] * w[3];
        }
        packed |= (u64)f2bf(tanhf(s)) << (16 * jj);
    }
    *(u64*)(hbuf + (size_t)b * HH + j0) = packed;
}

// ---- inline proj ----
template<int FRESH>
__device__ __forceinline__ void proj_tile(
    const unsigned short* hb, const unsigned short* __restrict__ Woutb,
    float* __restrict__ out, float (*pred)[16 * PP],
    int brow, int io, int wave, int lane, int lr, int lk, int tp, float boutv) {
    f32x4 oa = {0.f, 0.f, 0.f, 0.f};
    const unsigned short* ap = hb + (size_t)(brow + lr) * HH + (wave << 8) + lk;
    const unsigned short* wp = Woutb + (size_t)(io * 16 + lr) * HH + (wave << 8) + lk;
#pragma unroll
    for (int ks = 0; ks < 8; ++ks) {
        s8v a = ld16h<FRESH>(ap + ks * 32);
        s8v w = *(const s8v*)(wp + ks * 32);
        oa = __builtin_amdgcn_mfma_f32_16x16x32_bf16(a, w, oa, 0, 0, 0);
    }
    if (wave >= 1) {
#pragma unroll
        for (int r = 0; r < 4; ++r)
            pred[wave - 1][(((lane >> 4) << 2) + r) * PP + lr] = oa[r];
    }
    __syncthreads();
    if (wave == 0) {
#pragma unroll
        for (int r = 0; r < 4; ++r) {
            int rw = ((lane >> 4) << 2) + r;
            int idx = rw * PP + lr;
            float v = oa[r] + pred[0][idx] + pred[1][idx] + pred[2][idx] + boutv;
            out[(size_t)(brow + rw) * (TT * II) + (size_t)tp * II + io * 16 + lr] = sigm(v);
        }
    }
    __syncthreads();
}

// ---- round-6 full loop (proven passing): GEMM + gates + inline proj ----
template<int FRESH>
__device__ void run_full(const float* __restrict__ tgt, const unsigned short* __restrict__ Wperm,
                         const float* __restrict__ bihp, const float* __restrict__ bhhp,
                         unsigned short* hbuf, const unsigned short* __restrict__ Woutb,
                         const float* __restrict__ bout, float* __restrict__ out,
                         unsigned* flags,
                         float (*red)[64 * RP], float* gxn, float (*pred)[16 * PP]) {
    const int tid = threadIdx.x;
    const int wave = tid >> 6, lane = tid & 63;
    const int lr = lane & 15;
    const int lk = (lane >> 4) << 3;
    const int bid = blockIdx.x;
    const int m = bid >> 6, nt = bid & 63;
    const int brow = m * 64 + (nt >> 4) * 16;
    const int io = nt & 15;
    const float boutv = bout[io * 16 + lr];

    const int eb = lane;
    const int j4 = wave << 2;
    const int ob = nt * 48;
    float bir[4], biz[4], bixn[4], bihn[4];
#pragma unroll
    for (int jj = 0; jj < 4; ++jj) {
        int j = j4 + jj;
        bir[jj]  = bihp[ob + j] + bhhp[ob + j];
        biz[jj]  = bihp[ob + 16 + j] + bhhp[ob + 16 + j];
        bixn[jj] = bihp[ob + 32 + j];
        bihn[jj] = bhhp[ob + 32 + j];
    }

    s8v wreg[30];
    if (wave == 3) {
#pragma unroll
        for (int ks = 0; ks < 2; ++ks)
#pragma unroll
            for (int ni = 0; ni < 3; ++ni)
                wreg[ks * 3 + ni] = *(const s8v*)(Wperm +
                    (size_t)(nt * 48 + ni * 16 + lr) * K1 + 960 + ks * 32 + lk);
#pragma unroll
        for (int ks = 0; ks < 8; ++ks)
#pragma unroll
            for (int ni = 0; ni < 3; ++ni)
                wreg[6 + ks * 3 + ni] = *(const s8v*)(Wperm +
                    (size_t)(nt * 48 + ni * 16 + lr) * K1 + HH + ks * 32 + lk);
    } else {
#pragma unroll
        for (int ks = 0; ks < 10; ++ks)
#pragma unroll
            for (int ni = 0; ni < 3; ++ni)
                wreg[ks * 3 + ni] = *(const s8v*)(Wperm +
                    (size_t)(nt * 48 + ni * 16 + lr) * K1 + wave * 320 + ks * 32 + lk);
    }

    unsigned* gflags = flags + (m << 6);

    for (int t = 0; t < TT; ++t) {
        const unsigned short* hcur = hbuf + (size_t)(FRESH ? t : (t % 3)) * BBHH;
        unsigned short* hnxt = hbuf + (size_t)(FRESH ? (t + 1) : ((t + 1) % 3)) * BBHH;

        f32x4 acc[12];
#pragma unroll
        for (int i = 0; i < 12; ++i) acc[i] = (f32x4){0.f, 0.f, 0.f, 0.f};
        f32x4 accx[4];
#pragma unroll
        for (int i = 0; i < 4; ++i) accx[i] = (f32x4){0.f, 0.f, 0.f, 0.f};

        if (wave == 3) {
#pragma unroll
            for (int ks = 0; ks < 8; ++ks) {
                s8v xa[4];
#pragma unroll
                for (int mi = 0; mi < 4; ++mi)
                    xa[mi] = cvt8(tgt +
                        ((size_t)(m * 64 + mi * 16 + lr) * TT + t) * II + ks * 32 + lk);
#pragma unroll
                for (int mi = 0; mi < 4; ++mi) {
                    acc[mi * 3 + 0] = __builtin_amdgcn_mfma_f32_16x16x32_bf16(
                        xa[mi], wreg[6 + ks * 3 + 0], acc[mi * 3 + 0], 0, 0, 0);
                    acc[mi * 3 + 1] = __builtin_amdgcn_mfma_f32_16x16x32_bf16(
                        xa[mi], wreg[6 + ks * 3 + 1], acc[mi * 3 + 1], 0, 0, 0);
                    accx[mi] = __builtin_amdgcn_mfma_f32_16x16x32_bf16(
                        xa[mi], wreg[6 + ks * 3 + 2], accx[mi], 0, 0, 0);
                }
            }
        }

        if constexpr (!FRESH) {
            if (wave == 0) poll_range64(gflags, lane, (unsigned)t);
            __syncthreads();
        }

        if (wave < 3) {
            const unsigned* fp = gflags + wave * 20;
            poll_pair(fp, (unsigned)t);
#pragma unroll
            for (int ci = 0; ci < 10; ++ci) {
                s8v a[4];
#pragma unroll
                for (int mi = 0; mi < 4; ++mi)
                    a[mi] = ld16h<FRESH>(hcur +
                        (size_t)(m * 64 + mi * 16 + lr) * HH + wave * 320 + ci * 32 + lk);
                if (ci < 9) poll_pair(fp + 2 * (ci + 1), (unsigned)t);
#pragma unroll
                for (int mi = 0; mi < 4; ++mi)
#pragma unroll
                    for (int ni = 0; ni < 3; ++ni)
                        acc[mi * 3 + ni] = __builtin_amdgcn_mfma_f32_16x16x32_bf16(
                            a[mi], wreg[ci * 3 + ni], acc[mi * 3 + ni], 0, 0, 0);
            }
        } else {
            poll_pair(gflags + 60, (unsigned)t);
#pragma unroll
            for (int ks = 0; ks < 2; ++ks) {
                s8v a[4];
#pragma unroll
                for (int mi = 0; mi < 4; ++mi)
                    a[mi] = ld16h<FRESH>(hcur +
                        (size_t)(m * 64 + mi * 16 + lr) * HH + 960 + ks * 32 + lk);
                if (ks == 0) poll_pair(gflags + 62, (unsigned)t);
#pragma unroll
                for (int mi = 0; mi < 4; ++mi)
#pragma unroll
                    for (int ni = 0; ni < 3; ++ni)
                        acc[mi * 3 + ni] = __builtin_amdgcn_mfma_f32_16x16x32_bf16(
                            a[mi], wreg[ks * 3 + ni], acc[mi * 3 + ni], 0, 0, 0);
            }
#pragma unroll
            for (int mi = 0; mi < 4; ++mi)
#pragma unroll
                for (int r = 0; r < 4; ++r)
                    gxn[(mi * 16 + ((lane >> 4) << 2) + r) * GP + lr] = accx[mi][r];
        }

        {
            float* s = &red[wave][0];
#pragma unroll
            for (int mi = 0; mi < 4; ++mi)
#pragma unroll
                for (int ni = 0; ni < 3; ++ni)
#pragma unroll
                    for (int r = 0; r < 4; ++r)
                        s[(mi * 16 + ((lane >> 4) << 2) + r) * RP + ni * 16 + lr] =
                            acc[mi * 3 + ni][r];
        }
        __syncthreads();

        {
            const int bg = m * 64 + eb;
            const int jg = nt * 16 + j4;
            u64 hold8 = ld8h<FRESH>(hcur + (size_t)bg * HH + jg);
            u64 packed = 0;
#pragma unroll
            for (int jj = 0; jj < 4; ++jj) {
                int c = j4 + jj;
                int i0 = eb * RP + c;
                float ghr = red[0][i0] + red[1][i0] + red[2][i0] + red[3][i0];
                float ghz = red[0][i0 + 16] + red[1][i0 + 16] + red[2][i0 + 16] + red[3][i0 + 16];
                float ghn = red[0][i0 + 32] + red[1][i0 + 32] + red[2][i0 + 32] + red[3][i0 + 32];
                float gx  = gxn[eb * GP + c];
                float r   = sigm(ghr + bir[jj]);
                float zg  = sigm(ghz + biz[jj]);
                float n   = tanhf(gx + bixn[jj] + r * (ghn + bihn[jj]));
                float ho  = bf2f((unsigned short)(hold8 >> (16 * jj)));
                packed |= (u64)f2bf((1.f - zg) * n + zg * ho) << (16 * jj);
            }
            st8h(hnxt + (size_t)bg * HH + jg, packed);
        }

        asm volatile("s_waitcnt vmcnt(0)" ::: "memory");
        __syncthreads();
        if (tid == 0)
            __hip_atomic_store(gflags + nt, (unsigned)(t + 1), __ATOMIC_RELAXED,
                               __HIP_MEMORY_SCOPE_AGENT);

        if (t > 0) {
            poll_range16(gflags + (wave << 4), lr, (unsigned)t);
            proj_tile<FRESH>(hcur, Woutb, out, pred, brow, io, wave, lane, lr, lk,
                             t - 1, boutv);
        }
    }
    poll_range16(gflags + (wave << 4), lr, (unsigned)TT);
    proj_tile<FRESH>(hbuf + (size_t)(FRESH ? TT : (TT % 3)) * BBHH,
                     Woutb, out, pred, brow, io, wave, lane, lr, lk, TT - 1, boutv);
}

// name-split so the rocprof table reveals which mode actually runs
__global__ __launch_bounds__(256, 1) void dec_fresh(
    const float* __restrict__ tgt, const unsigned short* __restrict__ Wperm,
    const float* __restrict__ bihp, const float* __restrict__ bhhp,
    unsigned short* hbuf, const unsigned short* __restrict__ Woutb,
    const float* __restrict__ bout, float* __restrict__ out, unsigned* flags) {
    __shared__ float red[4][64 * RP];
    __shared__ float gxn[64 * GP];
    __shared__ float pred[3][16 * PP];
    run_full<1>(tgt, Wperm, bihp, bhhp, hbuf, Woutb, bout, out, flags, red, gxn, pred);
}
__global__ __launch_bounds__(256, 1) void dec_small(
    const float* __restrict__ tgt, const unsigned short* __restrict__ Wperm,
    const float* __restrict__ bihp, const float* __restrict__ bhhp,
    unsigned short* hbuf, const unsigned short* __restrict__ Woutb,
    const float* __restrict__ bout, float* __restrict__ out, unsigned* flags) {
    __shared__ float red[4][64 * RP];
    __shared__ float gxn[64 * GP];
    __shared__ float pred[3][16 * PP];
    run_full<0>(tgt, Wperm, bihp, bhhp, hbuf, Woutb, bout, out, flags, red, gxn, pred);
}

// ---- sync-stripped recurrence (3-slot, sc1 loads) for the compute ablation ----
template<int FRESH, int SYNC>
__device__ void run_rec(const float* __restrict__ tgt, const unsigned short* __restrict__ Wperm,
                        const float* __restrict__ bihp, const float* __restrict__ bhhp,
                        unsigned short* hbuf, unsigned* flags,
                        float (*red)[64 * RP], float* gxn) {
    const int tid = threadIdx.x;
    const int wave = tid >> 6, lane = tid & 63;
    const int lr = lane & 15;
    const int lk = (lane >> 4) << 3;
    const int bid = blockIdx.x;
    const int m = bid >> 6, nt = bid & 63;

    const int eb = lane;
    const int j4 = wave << 2;
    const int ob = nt * 48;
    float bir[4], biz[4], bixn[4], bihn[4];
#pragma unroll
    for (int jj = 0; jj < 4; ++jj) {
        int j = j4 + jj;
        bir[jj]  = bihp[ob + j] + bhhp[ob + j];
        biz[jj]  = bihp[ob + 16 + j] + bhhp[ob + 16 + j];
        bixn[jj] = bihp[ob + 32 + j];
        bihn[jj] = bhhp[ob + 32 + j];
    }

    s8v wreg[30];
    if (wave == 3) {
#pragma unroll
        for (int ks = 0; ks < 2; ++ks)
#pragma unroll
            for (int ni = 0; ni < 3; ++ni)
                wreg[ks * 3 + ni] = *(const s8v*)(Wperm +
                    (size_t)(nt * 48 + ni * 16 + lr) * K1 + 960 + ks * 32 + lk);
#pragma unroll
        for (int ks = 0; ks < 8; ++ks)
#pragma unroll
            for (int ni = 0; ni < 3; ++ni)
                wreg[6 + ks * 3 + ni] = *(const s8v*)(Wperm +
                    (size_t)(nt * 48 + ni * 16 + lr) * K1 + HH + ks * 32 + lk);
    } else {
#pragma unroll
        for (int ks = 0; ks < 10; ++ks)
#pragma unroll
            for (int ni = 0; ni < 3; ++ni)
                wreg[ks * 3 + ni] = *(const s8v*)(Wperm +
                    (size_t)(nt * 48 + ni * 16 + lr) * K1 + wave * 320 + ks * 32 + lk);
    }

    unsigned* gflags = flags + (m << 6);

    for (int t = 0; t < TT; ++t) {
        const unsigned short* hcur = hbuf + (size_t)(FRESH ? t : (t % 3)) * BBHH;
        unsigned short* hnxt = hbuf + (size_t)(FRESH ? (t + 1) : ((t + 1) % 3)) * BBHH;

        f32x4 acc[12];
#pragma unroll
        for (int i = 0; i < 12; ++i) acc[i] = (f32x4){0.f, 0.f, 0.f, 0.f};
        f32x4 accx[4];
#pragma unroll
        for (int i = 0; i < 4; ++i) accx[i] = (f32x4){0.f, 0.f, 0.f, 0.f};

        if (wave == 3) {
#pragma unroll
            for (int ks = 0; ks < 8; ++ks) {
                s8v xa[4];
#pragma unroll
                for (int mi = 0; mi < 4; ++mi)
                    xa[mi] = cvt8(tgt +
                        ((size_t)(m * 64 + mi * 16 + lr) * TT + t) * II + ks * 32 + lk);
#pragma unroll
                for (int mi = 0; mi < 4; ++mi) {
                    acc[mi * 3 + 0] = __builtin_amdgcn_mfma_f32_16x16x32_bf16(
                        xa[mi], wreg[6 + ks * 3 + 0], acc[mi * 3 + 0], 0, 0, 0);
                    acc[mi * 3 + 1] = __builtin_amdgcn_mfma_f32_16x16x32_bf16(
                        xa[mi], wreg[6 + ks * 3 + 1], acc[mi * 3 + 1], 0, 0, 0);
                    accx[mi] = __builtin_amdgcn_mfma_f32_16x16x32_bf16(
                        xa[mi], wreg[6 + ks * 3 + 2], accx[mi], 0, 0, 0);
                }
            }
        }

        if (wave < 3) {
            const unsigned* fp = gflags + wave * 20;
            if (SYNC) poll_pair(fp, (unsigned)t);
#pragma unroll
            for (int ci = 0; ci < 10; ++ci) {
                s8v a[4];
#pragma unroll
                for (int mi = 0; mi < 4; ++mi)
                    a[mi] = ld16h<FRESH>(hcur +
                        (size_t)(m * 64 + mi * 16 + lr) * HH + wave * 320 + ci * 32 + lk);
                if (SYNC && ci < 9) poll_pair(fp + 2 * (ci + 1), (unsigned)t);
#pragma unroll
                for (int mi = 0; mi < 4; ++mi)
#pragma unroll
                    for (int ni = 0; ni < 3; ++ni)
                        acc[mi * 3 + ni] = __builtin_amdgcn_mfma_f32_16x16x32_bf16(
                            a[mi], wreg[ci * 3 + ni], acc[mi * 3 + ni], 0, 0, 0);
            }
        } else {
            if (SYNC) poll_pair(gflags + 60, (unsigned)t);
#pragma unroll
            for (int ks = 0; ks < 2; ++ks) {
                s8v a[4];
#pragma unroll
                for (int mi = 0; mi < 4; ++mi)
                    a[mi] = ld16h<FRESH>(hcur +
                        (size_t)(m * 64 + mi * 16 + lr) * HH + 960 + ks * 32 + lk);
                if (SYNC && ks == 0) poll_pair(gflags + 62, (unsigned)t);
#pragma unroll
                for (int mi = 0; mi < 4; ++mi)
#pragma unroll
                    for (int ni = 0; ni < 3; ++ni)
                        acc[mi * 3 + ni] = __builtin_amdgcn_mfma_f32_16x16x32_bf16(
                            a[mi], wreg[ks * 3 + ni], acc[mi * 3 + ni], 0, 0, 0);
            }
#pragma unroll
            for (int mi = 0; mi < 4; ++mi)
#pragma unroll
                for (int r = 0; r < 4; ++r)
                    gxn[(mi * 16 + ((lane >> 4) << 2) + r) * GP + lr] = accx[mi][r];
        }

        {
            float* s = &red[wave][0];
#pragma unroll
            for (int mi = 0; mi < 4; ++mi)
#pragma unroll
                for (int ni = 0; ni < 3; ++ni)
#pragma unroll
                    for (int r = 0; r < 4; ++r)
                        s[(mi * 16 + ((lane >> 4) << 2) + r) * RP + ni * 16 + lr] =
                            acc[mi * 3 + ni][r];
        }
        __syncthreads();

        {
            const int bg = m * 64 + eb;
            const int jg = nt * 16 + j4;
            u64 hold8 = ld8h<FRESH>(hcur + (size_t)bg * HH + jg);
            u64 packed = 0;
#pragma unroll
            for (int jj = 0; jj < 4; ++jj) {
                int c = j4 + jj;
                int i0 = eb * RP + c;
                float ghr = red[0][i0] + red[1][i0] + red[2][i0] + red[3][i0];
                float ghz = red[0][i0 + 16] + red[1][i0 + 16] + red[2][i0 + 16] + red[3][i0 + 16];
                float ghn = red[0][i0 + 32] + red[1][i0 + 32] + red[2][i0 + 32] + red[3][i0 + 32];
                float gx  = gxn[eb * GP + c];
                float r   = sigm(ghr + bir[jj]);
                float zg  = sigm(ghz + biz[jj]);
                float n   = tanhf(gx + bixn[jj] + r * (ghn + bihn[jj]));
                float ho  = bf2f((unsigned short)(hold8 >> (16 * jj)));
                packed |= (u64)f2bf((1.f - zg) * n + zg * ho) << (16 * jj);
            }
            st8h(hnxt + (size_t)bg * HH + jg, packed);
        }

        if (SYNC) asm volatile("s_waitcnt vmcnt(0)" ::: "memory");
        __syncthreads();
        if (SYNC && tid == 0)
            __hip_atomic_store(gflags + nt, (unsigned)(t + 1), __ATOMIC_RELAXED,
                               __HIP_MEMORY_SCOPE_AGENT);
    }
}

// ======= ablations: ISOLATED buffers only (abl_hbuf/flags2/flags3/sink) =======

// effective-clock probe: 131072 dependent FMAs = 524288 cy = 218us @ 2.4GHz
__global__ __launch_bounds__(256, 1) void abl_clock_fresh(float* sink) {
    float a = (float)threadIdx.x * 1e-7f;
    for (int t = 0; t < TT; ++t)
        for (int i = 0; i < 512; ++i) a = __builtin_fmaf(a, 1.0000001f, 0.9999f);
    sink[blockIdx.x * 256 + threadIdx.x] = a;
}
__global__ __launch_bounds__(256, 1) void abl_clock_smallws(float* sink) {
    float a = (float)threadIdx.x * 1e-7f;
    for (int t = 0; t < TT; ++t)
        for (int i = 0; i < 512; ++i) a = __builtin_fmaf(a, 1.0000001f, 0.9999f);
    sink[blockIdx.x * 256 + threadIdx.x] = a;
}

// pure barrier: 256 x (flag store + 64-way poll)
__global__ __launch_bounds__(256, 1) void abl_flag(unsigned* f2) {
    const int tid = threadIdx.x, bid = blockIdx.x;
    const int m = bid >> 6, nt = bid & 63, wave = tid >> 6, lane = tid & 63;
    unsigned* g = f2 + (m << 6);
    for (int t = 0; t < TT; ++t) {
        __syncthreads();
        if (tid == 0)
            __hip_atomic_store(g + nt, (unsigned)(t + 1), __ATOMIC_RELAXED,
                               __HIP_MEMORY_SCOPE_AGENT);
        if (wave == 0) poll_range64(g, lane, (unsigned)(t + 1));
        __syncthreads();
    }
}

// barrier + h store/load round-trip on its OWN 3-slot buffer
__global__ __launch_bounds__(256, 1) void abl_hxchg(unsigned short* ahbuf, unsigned* f3,
                                                    float* sink) {
    const int tid = threadIdx.x, bid = blockIdx.x;
    const int m = bid >> 6, nt = bid & 63, wave = tid >> 6, lane = tid & 63;
    const int lr = lane & 15, lk = (lane >> 4) << 3;
    unsigned* g = f3 + (m << 6);
    const int bg = m * 64 + lane;
    const int jg = nt * 16 + (wave << 2);
    s8v acc = {0, 0, 0, 0, 0, 0, 0, 0};
    for (int t = 0; t < TT; ++t) {
        int snx = (t + 1) % 3, scr = t % 3;
        st8h(ahbuf + (size_t)snx * BBHH + (size_t)bg * HH + jg, (u64)(t + 1));
        asm volatile("s_waitcnt vmcnt(0)" ::: "memory");
        __syncthreads();
        if (tid == 0)
            __hip_atomic_store(g + nt, (unsigned)(t + 1), __ATOMIC_RELAXED,
                               __HIP_MEMORY_SCOPE_AGENT);
        if (wave == 0) poll_range64(g, lane, (unsigned)(t + 1));
        __syncthreads();
        const unsigned short* hc = ahbuf + (size_t)scr * BBHH;
        if (wave < 3) {
#pragma unroll
            for (int ci = 0; ci < 10; ++ci)
#pragma unroll
                for (int mi = 0; mi < 4; ++mi)
                    acc ^= hload16a(hc + (size_t)(m * 64 + mi * 16 + lr) * HH +
                                    wave * 320 + ci * 32 + lk);
        } else {
#pragma unroll
            for (int ks = 0; ks < 2; ++ks)
#pragma unroll
                for (int mi = 0; mi < 4; ++mi)
                    acc ^= hload16a(hc + (size_t)(m * 64 + mi * 16 + lr) * HH +
                                    960 + ks * 32 + lk);
        }
    }
    int s = 0;
#pragma unroll
    for (int i = 0; i < 8; ++i) s += acc[i];
    sink[(bid << 8) + tid] = (float)s;
}

// full compute chain, sync stripped, on its OWN 3-slot buffer
__global__ __launch_bounds__(256, 1) void abl_comp(
    const float* __restrict__ tgt, const unsigned short* __restrict__ Wperm,
    const float* __restrict__ bihp, const float* __restrict__ bhhp,
    unsigned short* ahbuf, unsigned* f3) {
    __shared__ float red[4][64 * RP];
    __shared__ float gxn[64 * GP];
    run_rec<0, 0>(tgt, Wperm, bihp, bhhp, ahbuf, f3, red, gxn);
}

extern "C" void kernel_launch(void* const* d_in, const int* in_sizes, int n_in,
                              void* d_out, int out_size, void* d_ws, size_t ws_size,
                              hipStream_t stream) {
    const float* z    = (const float*)d_in[0];
    const float* tgt  = (const float*)d_in[2];
    const float* Wz2h = (const float*)d_in[3];
    const float* bz2h = (const float*)d_in[4];
    const float* Wih  = (const float*)d_in[5];
    const float* Whh  = (const float*)d_in[6];
    const float* bih  = (const float*)d_in[7];
    const float* bhh  = (const float*)d_in[8];
    const float* Wout = (const float*)d_in[9];
    const float* bout = (const float*)d_in[10];
    float* out = (float*)d_out;

    char* ws = (char*)d_ws;
    unsigned short* Wperm = (unsigned short*)ws;               // 7,864,320
    float* bihp           = (float*)(ws + 7864320);            //    12,288
    float* bhhp           = (float*)(ws + 7876608);            //    12,288
    unsigned short* Woutb = (unsigned short*)(ws + 7888896);   //   524,288
    unsigned* flags       = (unsigned*)(ws + 8413184);         //     1,024
    unsigned* flags2      = (unsigned*)(ws + 8414208);         //     1,024
    unsigned* flags3      = (unsigned*)(ws + 8415232);         //     1,024
    float* sink           = (float*)(ws + 8416256);            //   262,144
    const size_t hbuf_off = 8678400ull;
    unsigned short* hbuf  = (unsigned short*)(ws + hbuf_off);

    const size_t slotB = (size_t)BBHH * 2;                     // 524,288
    const size_t need_big = hbuf_off + 257ull * slotB;         // 143,420,416
    const int fresh = (ws_size >= need_big) ? 1 : 0;
    const size_t nslots = fresh ? 257 : 3;
    const size_t abl_off = hbuf_off + nslots * slotB;
    const int abl_ok = (abl_off + 3 * slotB <= ws_size) ? 1 : 0;
    unsigned short* ahbuf = (unsigned short*)(ws + abl_off);

    hipMemsetAsync((void*)flags, 0, 3072, stream);
    hipLaunchKernelGGL(k_prep_w, dim3(GN), dim3(256), 0, stream, Whh, Wih, Wperm);
    hipLaunchKernelGGL(k_prep_misc, dim3(1024), dim3(256), 0, stream, bih, bhh, Wout,
                       bihp, bhhp, Woutb);
    hipLaunchKernelGGL(k_h0, dim3(BB), dim3(256), 0, stream, z, Wz2h, bz2h, hbuf);
    if (fresh)
        hipLaunchKernelGGL(dec_fresh, dim3(256), dim3(256), 0, stream,
                           tgt, Wperm, bihp, bhhp, hbuf, Woutb, bout, out, flags);
    else
        hipLaunchKernelGGL(dec_small, dim3(256), dim3(256), 0, stream,
                           tgt, Wperm, bihp, bhhp, hbuf, Woutb, bout, out, flags);

    // ---- diagnostics: isolated buffers, cannot perturb real state ----
    if (fresh)
        hipLaunchKernelGGL(abl_clock_fresh, dim3(256), dim3(256), 0, stream, sink);
    else
        hipLaunchKernelGGL(abl_clock_smallws, dim3(256), dim3(256), 0, stream, sink);
    hipLaunchKernelGGL(abl_flag, dim3(256), dim3(256), 0, stream, flags2);
    if (abl_ok) {
        hipLaunchKernelGGL(abl_hxchg, dim3(256), dim3(256), 0, stream, ahbuf, flags3, sink);
        hipLaunchKernelGGL(abl_comp, dim3(256), dim3(256), 0, stream,
                           tgt, Wperm, bihp, bhhp, ahbuf, flags3);
    }
}

// Round 10
// 6438.396 us; speedup vs baseline: 2.1580x; 2.1580x over previous
//
#include <hip/hip_runtime.h>

#define BB 256
#define TT 256
#define II 256
#define HH 1024
#define LL 128
#define K1 1280   // HH + II
#define GN 3072   // 3*HH
#define BBHH (BB * HH)

#define RP2 97    // red row stride (floats)
#define GP2 33    // gxn row stride
#define PP 20     // pred row stride

typedef short s8v    __attribute__((ext_vector_type(8)));
typedef float f32x4  __attribute__((ext_vector_type(4)));
typedef float f4v    __attribute__((ext_vector_type(4)));
typedef unsigned long long u64;
typedef unsigned short us;

__device__ __forceinline__ us f2bf(float f) {
    unsigned u = __float_as_uint(f);
    u += 0x7fffu + ((u >> 16) & 1u);
    return (us)(u >> 16);
}
__device__ __forceinline__ float bf2f(us h) {
    return __uint_as_float(((unsigned)h) << 16);
}
__device__ __forceinline__ float sigm(float x) { return 1.0f / (1.0f + __expf(-x)); }

__device__ __forceinline__ s8v cvt8(const float* __restrict__ p) {
    const f4v lo = *(const f4v*)p;
    const f4v hi = *(const f4v*)(p + 4);
    s8v r;
    r[0] = (short)f2bf(lo[0]); r[1] = (short)f2bf(lo[1]);
    r[2] = (short)f2bf(lo[2]); r[3] = (short)f2bf(lo[3]);
    r[4] = (short)f2bf(hi[0]); r[5] = (short)f2bf(hi[1]);
    r[6] = (short)f2bf(hi[2]); r[7] = (short)f2bf(hi[3]);
    return r;
}

// sc1 (coherence-point) 16B load, for the 3-slot fallback
__device__ __forceinline__ s8v hload16a(const us* p) {
    union { u64 q[2]; s8v v; } u;
    u.q[0] = __hip_atomic_load((const u64*)p, __ATOMIC_RELAXED, __HIP_MEMORY_SCOPE_AGENT);
    u.q[1] = __hip_atomic_load((const u64*)p + 1, __ATOMIC_RELAXED, __HIP_MEMORY_SCOPE_AGENT);
    return u.v;
}
template<int FRESH> __device__ __forceinline__ s8v ld16h(const us* p) {
    if constexpr (FRESH) return *(const s8v*)p;   // fresh slot address: L1-cold, safe
    else return hload16a(p);
}
template<int FRESH> __device__ __forceinline__ u64 ld8h(const us* p) {
    if constexpr (FRESH) return *(const u64*)p;
    else return __hip_atomic_load((const u64*)p, __ATOMIC_RELAXED, __HIP_MEMORY_SCOPE_AGENT);
}
// h store: LOCAL -> plain (write-through into this XCD's L2); GLOBAL -> sc1
template<int LOCAL> __device__ __forceinline__ void h_store8(us* p, u64 v) {
    if constexpr (LOCAL) *(u64*)p = v;
    else __hip_atomic_store((u64*)p, v, __ATOMIC_RELAXED, __HIP_MEMORY_SCOPE_AGENT);
}
// flags: ALWAYS agent scope (round-9 post-mortem: workgroup-scope RMW probes can
// be serviced from L1 -> poller spins on stale line -> guard-expiry deadlock).
__device__ __forceinline__ void flag_store(unsigned* p, unsigned v) {
    __hip_atomic_store(p, v, __ATOMIC_RELAXED, __HIP_MEMORY_SCOPE_AGENT);
}
__device__ __forceinline__ unsigned flag_probe(unsigned* p) {
    return __hip_atomic_load(p, __ATOMIC_RELAXED, __HIP_MEMORY_SCOPE_AGENT);
}
// wave-0 group barrier: all 32 member flags >= t
__device__ __forceinline__ void group_wait(unsigned* gf, int lane, unsigned t) {
    if (t == 0) return;
    int guard = 0;
    for (;;) {
        unsigned v = t;
        if (lane < 32) v = flag_probe(gf + lane);
        if (__ballot(v >= t) == ~0ull) break;
        __builtin_amdgcn_s_sleep(1);
        if (++guard > (1 << 18)) break;   // safety valve
    }
    asm volatile("" ::: "memory");
}

// ---- prep: permuted gate weights, 96-row blocks per WG ----
// Row o = nt*96 + gate*32 + jj  <-  source gate*HH + (nt*32+jj).
// Cols [0,1024) = W_hh row; [1024,1280) = W_ih row.
__global__ void k_prep_w(const float* __restrict__ Whh, const float* __restrict__ Wih,
                         us* __restrict__ Wperm) {
    int o = blockIdx.x;                 // 3072
    int ntt = o / 96, q = o - ntt * 96;
    int gate = q >> 5, jj = q & 31;
    int src = gate * HH + ntt * 32 + jj;
    const float* sh = Whh + (size_t)src * HH;
    const float* si = Wih + (size_t)src * II;
    us* dst = Wperm + (size_t)o * K1;
    for (int k = threadIdx.x; k < K1; k += 256)
        dst[k] = f2bf(k < HH ? sh[k] : si[k - HH]);
}

__global__ void k_prep_misc(const float* __restrict__ bih, const float* __restrict__ bhh,
                            const float* __restrict__ Wout,
                            float* __restrict__ bihp, float* __restrict__ bhhp,
                            us* __restrict__ Woutb) {
    int idx = blockIdx.x * 256 + threadIdx.x;
    if (idx < GN) {
        int ntt = idx / 96, q = idx - ntt * 96;
        int gate = q >> 5, jj = q & 31;
        int src = gate * HH + ntt * 32 + jj;
        bihp[idx] = bih[src];
        bhhp[idx] = bhh[src];
    }
    for (size_t i = (size_t)blockIdx.x * 256 + threadIdx.x; i < (size_t)II * HH;
         i += (size_t)gridDim.x * 256)
        Woutb[i] = f2bf(Wout[i]);
}

__global__ void k_h0(const float* __restrict__ z, const float* __restrict__ Wz,
                     const float* __restrict__ bz, us* __restrict__ hbuf) {
    int b = blockIdx.x;
    int j0 = threadIdx.x * 4;
    const f4v* zr = (const f4v*)(z + (size_t)b * LL);
    u64 packed = 0;
#pragma unroll
    for (int jj = 0; jj < 4; ++jj) {
        int j = j0 + jj;
        const f4v* wr = (const f4v*)(Wz + (size_t)j * LL);
        float s = bz[j];
#pragma unroll
        for (int i = 0; i < LL / 4; ++i) {
            f4v a = zr[i], w = wr[i];
            s += a[0] * w[0] + a[1] * w[1] + a[2] * w[2] + a[3] * w[3];
        }
        packed |= (u64)f2bf(tanhf(s)) << (16 * jj);
    }
    *(u64*)(hbuf + (size_t)b * HH + j0) = packed;
}

// output projection: one 16x16 tile, K=1024 split across 4 waves
template<int FRESH>
__device__ __forceinline__ void proj_tile(
    const us* hb, const us* __restrict__ Woutb,
    float* __restrict__ out, float (*pred)[16 * PP],
    int brow, int it, int wave, int lane, int lr, int lk, int tp, float boutv) {
    f32x4 oa = {0.f, 0.f, 0.f, 0.f};
    const us* ap = hb + (size_t)(brow + lr) * HH + (wave << 8) + lk;
    const us* wp = Woutb + (size_t)(it * 16 + lr) * HH + (wave << 8) + lk;
#pragma unroll
    for (int ks = 0; ks < 8; ++ks) {
        s8v a = ld16h<FRESH>(ap + ks * 32);
        s8v w = *(const s8v*)(wp + ks * 32);
        oa = __builtin_amdgcn_mfma_f32_16x16x32_bf16(a, w, oa, 0, 0, 0);
    }
    if (wave >= 1) {
#pragma unroll
        for (int r = 0; r < 4; ++r)
            pred[wave - 1][(((lane >> 4) << 2) + r) * PP + lr] = oa[r];
    }
    __syncthreads();
    if (wave == 0) {
#pragma unroll
        for (int r = 0; r < 4; ++r) {
            int rw = ((lane >> 4) << 2) + r;
            int idx = rw * PP + lr;
            float v = oa[r] + pred[0][idx] + pred[1][idx] + pred[2][idx] + boutv;
            out[(size_t)(brow + rw) * (TT * II) + (size_t)tp * II + it * 16 + lr] = sigm(v);
        }
    }
    __syncthreads();
}

// ---- main loop: 8 groups (bid%8 -> one XCD) x 32 WGs; WG = 32 batches x 96 gate rows ----
template<int LOCAL, int FRESH>
__device__ void run9(const float* __restrict__ tgt, const us* __restrict__ Wperm,
                     const float* __restrict__ bihp, const float* __restrict__ bhhp,
                     us* hbuf, const us* __restrict__ Woutb,
                     const float* __restrict__ bout, float* __restrict__ out,
                     unsigned* flags,
                     float (*red)[32 * RP2], float* gxn, float (*pred)[16 * PP]) {
    const int tid = threadIdx.x;
    const int wave = tid >> 6, lane = tid & 63;
    const int lr = lane & 15;
    const int lk = (lane >> 4) << 3;
    const int hi4 = ((lane >> 4) << 2);
    const int bid = blockIdx.x;
    const int g = bid & 7, nt = bid >> 3;
    const int bt = nt >> 4, it = nt & 15;
    const int brow = g * 32 + bt * 16;
    const float boutv = bout[it * 16 + lr];

    // epilogue ownership: batch eb (0..31), 4 j starting at jq*4
    const int eb = tid & 31, jq = tid >> 5;
    const int ob = nt * 96;
    float bir[4], biz[4], bixn[4], bihn[4];
#pragma unroll
    for (int jj = 0; jj < 4; ++jj) {
        int lj = jq * 4 + jj;
        bir[jj]  = bihp[ob + lj] + bhhp[ob + lj];
        biz[jj]  = bihp[ob + 32 + lj] + bhhp[ob + 32 + lj];
        bixn[jj] = bihp[ob + 64 + lj];
        bihn[jj] = bhhp[ob + 64 + lj];
    }

    unsigned* gflags = flags + (g << 6);   // 32 words used, 64-stride padding

    for (int t = 0; t < TT; ++t) {
        const us* hcur = hbuf + (size_t)(FRESH ? t : (t % 3)) * BBHH;
        us* hnxt = hbuf + (size_t)(FRESH ? (t + 1) : ((t + 1) % 3)) * BBHH;

        f32x4 acc[12];   // [mi*6+ni]
#pragma unroll
        for (int i = 0; i < 12; ++i) acc[i] = (f32x4){0.f, 0.f, 0.f, 0.f};
        f32x4 accx[4];   // [mi*2 + (ni-4)] : x-part of n-gate
#pragma unroll
        for (int i = 0; i < 4; ++i) accx[i] = (f32x4){0.f, 0.f, 0.f, 0.f};

        // wave 3: x-part GEMM BEFORE the barrier (constant X)
        if (wave == 3) {
#pragma unroll
            for (int ks = 0; ks < 8; ++ks) {
                const int k0 = ks * 32 + lk;
                s8v xa[2], w[6];
#pragma unroll
                for (int mi = 0; mi < 2; ++mi)
                    xa[mi] = cvt8(tgt + ((size_t)(g * 32 + mi * 16 + lr) * TT + t) * II + k0);
#pragma unroll
                for (int ni = 0; ni < 6; ++ni)
                    w[ni] = *(const s8v*)(Wperm + (size_t)(ob + ni * 16 + lr) * K1 + HH + k0);
#pragma unroll
                for (int mi = 0; mi < 2; ++mi) {
#pragma unroll
                    for (int ni = 0; ni < 4; ++ni)
                        acc[mi * 6 + ni] = __builtin_amdgcn_mfma_f32_16x16x32_bf16(
                            xa[mi], w[ni], acc[mi * 6 + ni], 0, 0, 0);
                    accx[mi * 2 + 0] = __builtin_amdgcn_mfma_f32_16x16x32_bf16(
                        xa[mi], w[4], accx[mi * 2 + 0], 0, 0, 0);
                    accx[mi * 2 + 1] = __builtin_amdgcn_mfma_f32_16x16x32_bf16(
                        xa[mi], w[5], accx[mi * 2 + 1], 0, 0, 0);
                }
            }
        }

        // barrier: all 32 group members have published h_t
        if (wave == 0) group_wait(gflags, lane, (unsigned)t);
        __syncthreads();

        // h-part GEMM
        if (wave < 3) {
#pragma unroll
            for (int ci = 0; ci < 10; ++ci) {
                const int k0 = wave * 320 + ci * 32 + lk;
                s8v a[2], w[6];
#pragma unroll
                for (int mi = 0; mi < 2; ++mi)
                    a[mi] = ld16h<FRESH>(hcur + (size_t)(g * 32 + mi * 16 + lr) * HH + k0);
#pragma unroll
                for (int ni = 0; ni < 6; ++ni)
                    w[ni] = *(const s8v*)(Wperm + (size_t)(ob + ni * 16 + lr) * K1 + k0);
#pragma unroll
                for (int mi = 0; mi < 2; ++mi)
#pragma unroll
                    for (int ni = 0; ni < 6; ++ni)
                        acc[mi * 6 + ni] = __builtin_amdgcn_mfma_f32_16x16x32_bf16(
                            a[mi], w[ni], acc[mi * 6 + ni], 0, 0, 0);
            }
        } else {
#pragma unroll
            for (int ks = 0; ks < 2; ++ks) {
                const int k0 = 960 + ks * 32 + lk;
                s8v a[2], w[6];
#pragma unroll
                for (int mi = 0; mi < 2; ++mi)
                    a[mi] = ld16h<FRESH>(hcur + (size_t)(g * 32 + mi * 16 + lr) * HH + k0);
#pragma unroll
                for (int ni = 0; ni < 6; ++ni)
                    w[ni] = *(const s8v*)(Wperm + (size_t)(ob + ni * 16 + lr) * K1 + k0);
#pragma unroll
                for (int mi = 0; mi < 2; ++mi)
#pragma unroll
                    for (int ni = 0; ni < 6; ++ni)
                        acc[mi * 6 + ni] = __builtin_amdgcn_mfma_f32_16x16x32_bf16(
                            a[mi], w[ni], acc[mi * 6 + ni], 0, 0, 0);
            }
#pragma unroll
            for (int mi = 0; mi < 2; ++mi)
#pragma unroll
                for (int n2 = 0; n2 < 2; ++n2)
#pragma unroll
                    for (int r = 0; r < 4; ++r)
                        gxn[(mi * 16 + hi4 + r) * GP2 + n2 * 16 + lr] = accx[mi * 2 + n2][r];
        }

        // all 4 waves write partials; epilogue sums the 4 sets
        {
            float* s = &red[wave][0];
#pragma unroll
            for (int mi = 0; mi < 2; ++mi)
#pragma unroll
                for (int ni = 0; ni < 6; ++ni)
#pragma unroll
                    for (int r = 0; r < 4; ++r)
                        s[(mi * 16 + hi4 + r) * RP2 + ni * 16 + lr] = acc[mi * 6 + ni][r];
        }
        __syncthreads();

        // gate epilogue: thread (eb, jq*4..+3) -> one 8B h store
        {
            const int bg = g * 32 + eb;
            const int jbase = nt * 32 + jq * 4;
            u64 hold8 = ld8h<FRESH>(hcur + (size_t)bg * HH + jbase);
            u64 packed = 0;
#pragma unroll
            for (int jj = 0; jj < 4; ++jj) {
                int lj = jq * 4 + jj;
                float ghr = red[0][eb * RP2 + lj] + red[1][eb * RP2 + lj] +
                            red[2][eb * RP2 + lj] + red[3][eb * RP2 + lj];
                float ghz = red[0][eb * RP2 + 32 + lj] + red[1][eb * RP2 + 32 + lj] +
                            red[2][eb * RP2 + 32 + lj] + red[3][eb * RP2 + 32 + lj];
                float ghn = red[0][eb * RP2 + 64 + lj] + red[1][eb * RP2 + 64 + lj] +
                            red[2][eb * RP2 + 64 + lj] + red[3][eb * RP2 + 64 + lj];
                float gx  = gxn[eb * GP2 + lj];
                float r   = sigm(ghr + bir[jj]);
                float zg  = sigm(ghz + biz[jj]);
                float n   = tanhf(gx + bixn[jj] + r * (ghn + bihn[jj]));
                float ho  = bf2f((us)(hold8 >> (16 * jj)));
                packed |= (u64)f2bf((1.f - zg) * n + zg * ho) << (16 * jj);
            }
            h_store8<LOCAL>(hnxt + (size_t)bg * HH + jbase, packed);
        }

        // arrive: drain h stores (into local L2 / coherence point), then signal.
        // Peer ordering: flag visible (L3) => vmcnt(0) done => h in this XCD's L2,
        // which is exactly where same-XCD peers read it.
        asm volatile("s_waitcnt vmcnt(0)" ::: "memory");
        __syncthreads();
        if (tid == 0) flag_store(gflags + nt, (unsigned)(t + 1));

        // project y_{t-1} from h_t (fully ready since top-of-iteration barrier)
        if (t > 0)
            proj_tile<FRESH>(hcur, Woutb, out, pred, brow, it, wave, lane, lr, lk,
                             t - 1, boutv);
    }

    // tail: y_{T-1} from h_T
    if (wave == 0) group_wait(gflags, lane, (unsigned)TT);
    __syncthreads();
    proj_tile<FRESH>(hbuf + (size_t)(FRESH ? TT : (TT % 3)) * BBHH,
                     Woutb, out, pred, brow, it, wave, lane, lr, lk, TT - 1, boutv);
}

__global__ __launch_bounds__(256, 1) void dec10(
    const float* __restrict__ tgt, const us* __restrict__ Wperm,
    const float* __restrict__ bihp, const float* __restrict__ bhhp,
    us* hbuf, const us* __restrict__ Woutb,
    const float* __restrict__ bout, float* __restrict__ out,
    unsigned* xcdarr, unsigned* gstart, unsigned* flags, int fresh) {
    __shared__ float red[4][32 * RP2];
    __shared__ float gxn[32 * GP2];
    __shared__ float pred[3][16 * PP];
    __shared__ int lflag;

    const int tid = threadIdx.x, bid = blockIdx.x;
    const int g = bid & 7;

    unsigned myxcd;
    asm volatile("s_getreg_b32 %0, hwreg(HW_REG_XCC_ID)" : "=s"(myxcd));

    // census publish + global rendezvous (coherence-point atomics)
    if (tid == 0) {
        __hip_atomic_store(xcdarr + bid, myxcd + 1u, __ATOMIC_RELAXED, __HIP_MEMORY_SCOPE_AGENT);
        __hip_atomic_fetch_add(gstart, 1u, __ATOMIC_RELEASE, __HIP_MEMORY_SCOPE_AGENT);
        int guard = 0;
        while (__hip_atomic_load(gstart, __ATOMIC_ACQUIRE, __HIP_MEMORY_SCOPE_AGENT) < 256u) {
            __builtin_amdgcn_s_sleep(8);
            if (++guard > (1 << 20)) break;
        }
    }
    __syncthreads();
    // census read: group member nt's bid = g + 8*nt
    if (tid < 64) {
        unsigned v = (tid < 32)
            ? __hip_atomic_load(xcdarr + g + 8 * tid, __ATOMIC_RELAXED, __HIP_MEMORY_SCOPE_AGENT)
            : (myxcd + 1u);
        unsigned long long b = __ballot(v == myxcd + 1u);
        if (tid == 0) lflag = (b == ~0ull) ? 1 : 0;
    }
    __syncthreads();
    const int local = lflag;

    if (fresh) {
        if (local)
            run9<1, 1>(tgt, Wperm, bihp, bhhp, hbuf, Woutb, bout, out, flags, red, gxn, pred);
        else
            run9<0, 1>(tgt, Wperm, bihp, bhhp, hbuf, Woutb, bout, out, flags, red, gxn, pred);
    } else {
        run9<0, 0>(tgt, Wperm, bihp, bhhp, hbuf, Woutb, bout, out, flags, red, gxn, pred);
    }
}

extern "C" void kernel_launch(void* const* d_in, const int* in_sizes, int n_in,
                              void* d_out, int out_size, void* d_ws, size_t ws_size,
                              hipStream_t stream) {
    const float* z    = (const float*)d_in[0];
    const float* tgt  = (const float*)d_in[2];
    const float* Wz2h = (const float*)d_in[3];
    const float* bz2h = (const float*)d_in[4];
    const float* Wih  = (const float*)d_in[5];
    const float* Whh  = (const float*)d_in[6];
    const float* bih  = (const float*)d_in[7];
    const float* bhh  = (const float*)d_in[8];
    const float* Wout = (const float*)d_in[9];
    const float* bout = (const float*)d_in[10];
    float* out = (float*)d_out;

    char* ws = (char*)d_ws;
    us* Wperm        = (us*)ws;                          // 7,864,320
    float* bihp      = (float*)(ws + 7864320);           //    12,288
    float* bhhp      = (float*)(ws + 7876608);           //    12,288
    us* Woutb        = (us*)(ws + 7888896);              //   524,288
    unsigned* xcdarr = (unsigned*)(ws + 8413184);        //     1,024
    unsigned* gstart = (unsigned*)(ws + 8414208);        //       128
    unsigned* flags  = (unsigned*)(ws + 8414336);        //     2,048 (8 grp x 64 words)
    us* hbuf         = (us*)(ws + 8416512);              // 257 or 3 slots x 524,288

    const size_t slotB = (size_t)BBHH * 2;
    const size_t need_big = 8416512ull + 257ull * slotB; // 143,158,528
    const int fresh = (ws_size >= need_big) ? 1 : 0;

    hipMemsetAsync((void*)xcdarr, 0, 3328, stream);
    hipLaunchKernelGGL(k_prep_w, dim3(GN), dim3(256), 0, stream, Whh, Wih, Wperm);
    hipLaunchKernelGGL(k_prep_misc, dim3(1024), dim3(256), 0, stream, bih, bhh, Wout,
                       bihp, bhhp, Woutb);
    hipLaunchKernelGGL(k_h0, dim3(BB), dim3(256), 0, stream, z, Wz2h, bz2h, hbuf);
    hipLaunchKernelGGL(dec10, dim3(256), dim3(256), 0, stream,
                       tgt, Wperm, bihp, bhhp, hbuf, Woutb, bout, out,
                       xcdarr, gstart, flags, fresh);
}